// Round 7
// baseline (341.447 us; speedup 1.0000x reference)
//
#include <hip/hip_runtime.h>
#include <hip/hip_bf16.h>
#include <cstdint>

// Problem constants
constexpr int Bb = 8, Cc = 256, Hh = 64, Ww = 64, Nn = 4096;
constexpr int KD = 128, VD = 256, HP = 66; // HP = padded spatial (64+2)

typedef __attribute__((ext_vector_type(8))) short short8_t;   // 8 bf16 (4 VGPR) MFMA frag
typedef __attribute__((ext_vector_type(4))) short shortx4;    // 4 bf16 packed store
typedef __attribute__((ext_vector_type(4))) float floatx4;    // MFMA accumulator

// kScale = log2(e)/sqrt(128); P = exp2(2*kScale*dot - kScale*sqi - kScale*sqj)
constexpr float kScale = 0.08838834764831845f * 1.4426950408889634f;
constexpr float kTwoK  = 2.0f * kScale;

static __device__ __forceinline__ ushort f2bf(float f) {
    union { float f; uint32_t u; } v{f};
    uint32_t r = v.u + 0x7FFFu + ((v.u >> 16) & 1u);  // RNE
    return (ushort)(r >> 16);
}
static __device__ __forceinline__ float bf2f(ushort b) {
    union { uint32_t u; float f; } v{(uint32_t)b << 16};
    return v.f;
}
// pack two f32 -> two bf16 in one u32 (RNE), single HW inst
static __device__ __forceinline__ uint32_t pk_bf16(float a, float b) {
    uint32_t r;
    asm("v_cvt_pk_bf16_f32 %0, %1, %2" : "=v"(r) : "v"(a), "v"(b));
    return r;
}

// async global->LDS, 16B per lane; lds base must be wave-uniform (HW adds lane*16)
static __device__ __forceinline__ void gload_lds16(const void* g, void* l) {
    __builtin_amdgcn_global_load_lds((const __attribute__((address_space(1))) uint32_t*)g,
                                     (__attribute__((address_space(3))) uint32_t*)l, 16, 0, 0);
}

// ---------------------------------------------------------------------------
// K1: x[b][c][y][x] (f32) -> xpad[b][y+1][x+1][c] (bf16, channel-last).
// 1-D grid, b = bid&7 so batch b stays on XCD b (round-robin dispatch).
__global__ __launch_bounds__(256) void pad_transpose(const float* __restrict__ x,
                                                     ushort* __restrict__ xpad) {
    int bid = blockIdx.x;
    int b = bid & 7, rest = bid >> 3;
    int y = rest & 63, cg = rest >> 6;   // cg: 64-channel group
    int t = threadIdx.x;
    __shared__ float tile[64][65];
    int xcol = t & 63;
    int crow = t >> 6;  // 0..3
    const float* xb = x + ((size_t)(b * Cc + cg * 64) * Nn) + y * 64;
#pragma unroll
    for (int i = 0; i < 16; i++) {
        int c = crow + i * 4;
        tile[c][xcol] = xb[(size_t)c * Nn + xcol];
    }
    __syncthreads();
    int c = t & 63;
    int x4 = t >> 6;
    ushort* dst = xpad + (((size_t)(b * HP + (y + 1)) * HP) + 1) * Cc + cg * 64 + c;
#pragma unroll
    for (int i = 0; i < 16; i++) {
        int xx = x4 + i * 4;
        dst[(size_t)xx * Cc] = f2bf(tile[c][xx]);
    }
}

// ---------------------------------------------------------------------------
// K2: repack weights w[oc][c][3][3] (f32) -> wt[r][oc][c] (bf16), r = dy*3+dx
__global__ __launch_bounds__(256) void repack_w(const float* __restrict__ kw,
                                                const float* __restrict__ vw,
                                                ushort* __restrict__ wtk,
                                                ushort* __restrict__ wtv) {
    int idx = blockIdx.x * 256 + threadIdx.x;
    const int nk = KD * Cc;   // 32768
    const int nv = VD * Cc;   // 65536
    if (idx < nk) {
        const float* src = kw + (size_t)idx * 9;
        int oc = idx / Cc, c = idx % Cc;
#pragma unroll
        for (int r = 0; r < 9; r++) wtk[((size_t)r * KD + oc) * Cc + c] = f2bf(src[r]);
    } else if (idx < nk + nv) {
        int j = idx - nk;
        const float* src = vw + (size_t)j * 9;
        int oc = j / Cc, c = j % Cc;
#pragma unroll
        for (int r = 0; r < 9; r++) wtv[((size_t)r * VD + oc) * Cc + c] = f2bf(src[r]);
    }
}

// ---------------------------------------------------------------------------
// K3: implicit-GEMM conv3x3 via MFMA, weight slab LDS-staged (as round 6).
template <int MODE, int OC>
__global__ __launch_bounds__(256) void conv_gemm(const ushort* __restrict__ xpad,
                                                 const ushort* __restrict__ wt,
                                                 const float* __restrict__ bias,
                                                 ushort* __restrict__ kt_out,
                                                 float* __restrict__ f32_out,
                                                 ushort* __restrict__ vb_out) {
    int bid = blockIdx.x;
    int b = bid & 7;
    int ocg, y;
    if (OC == 128) { ocg = 0; y = bid >> 3; }
    else           { ocg = (bid >> 3) & 1; y = bid >> 4; }
    int lane = threadIdx.x & 63, wv = threadIdx.x >> 6;
    int l15 = lane & 15, g = lane >> 4;
    int oc0 = ocg * 128;
    const int swzA = l15 & 7;

    __shared__ ushort wslab[2][128 * 128];   // 2 x 32KB weight half-slabs

    size_t wsoff[8];
    int ldsrow[8];
#pragma unroll
    for (int h = 0; h < 8; h++) {
        int row = wv * 32 + h * 4 + (lane >> 4);      // oc row this lane stages
        wsoff[h] = (size_t)row * Cc + (((lane & 15) ^ (row & 7)) * 8);
        ldsrow[h] = (wv * 32 + h * 4) * 128;
    }

    floatx4 acc[8];
#pragma unroll
    for (int m = 0; m < 8; m++) acc[m] = (floatx4){0.f, 0.f, 0.f, 0.f};

    const ushort* xb = xpad + ((size_t)b * HP * HP) * Cc;
    int xcol = wv * 16 + l15;  // output x position (wave's 16 columns)

    auto stage = [&](int hs, int bi) {
        int r = hs >> 1, hc = hs & 1;
        const ushort* wb = wt + ((size_t)r * OC + oc0) * Cc + hc * 128;
#pragma unroll
        for (int h = 0; h < 8; h++)
            gload_lds16(wb + wsoff[h], &wslab[bi][ldsrow[h]]);
    };

    stage(0, 0);
    __syncthreads();   // implicit vmcnt(0): slab 0 resident

#pragma unroll 1
    for (int hs = 0; hs < 18; ++hs) {
        int bi = hs & 1;
        if (hs < 17) stage(hs + 1, bi ^ 1);   // prefetch; drained by end barrier

        int r = hs >> 1, hc = hs & 1;
        int dy = r / 3, dx = r % 3;
        const ushort* bsrc = xb + ((size_t)(y + dy) * HP + xcol + dx) * Cc + hc * 128 + g * 8;
#pragma unroll
        for (int cc = 0; cc < 4; cc++) {      // 4 k-steps of 32 channels
            short8_t bfrag = *(const short8_t*)(bsrc + cc * 32);
#pragma unroll
            for (int m = 0; m < 8; m++) {
                short8_t afrag = *(const short8_t*)&wslab[bi][(m * 16 + l15) * 128 + ((cc * 4 + g) ^ swzA) * 8];
                acc[m] = __builtin_amdgcn_mfma_f32_16x16x32_bf16(afrag, bfrag, acc[m], 0, 0, 0);
            }
        }
        __syncthreads();   // reads done + prefetch drained
    }

    int pos = y * 64 + xcol;
    if (MODE == 0) {
        ushort* kt = kt_out + ((size_t)(b * Nn + pos)) * KD;
#pragma unroll
        for (int m = 0; m < 8; m++) {
            floatx4 bv = *(const floatx4*)(bias + m * 16 + g * 4);
            shortx4 pk;
#pragma unroll
            for (int r = 0; r < 4; r++) pk[r] = (short)f2bf(acc[m][r] + bv[r]);
            *(shortx4*)(kt + m * 16 + g * 4) = pk;
        }
    } else {
#pragma unroll
        for (int m = 0; m < 8; m++) {
            floatx4 bv = *(const floatx4*)(bias + oc0 + m * 16 + g * 4);
#pragma unroll
            for (int r = 0; r < 4; r++) {
                int oc = oc0 + m * 16 + g * 4 + r;
                float v = acc[m][r] + bv[r];
                f32_out[((size_t)(b * 512 + oc)) * Nn + pos] = v;       // d_out f32
                vb_out[((size_t)(b * VD + oc)) * Nn + pos] = f2bf(v);   // bf16 for PV MFMA
            }
        }
    }
}

// ---------------------------------------------------------------------------
// K4: sq2[b*N+pos] = kScale * sum_ch Kt[pos][ch]^2 (scale pre-folded for attn).
__global__ __launch_bounds__(256) void sq_kernel(const ushort* __restrict__ kt,
                                                 float* __restrict__ sq) {
    int bid = blockIdx.x;
    int idx = (bid & 7) * Nn + (bid >> 3) * 256 + threadIdx.x;
    const ushort* src = kt + (size_t)idx * KD;
    float s = 0.f;
#pragma unroll
    for (int i = 0; i < 16; i++) {
        short8_t v = *(const short8_t*)(src + i * 8);
#pragma unroll
        for (int e = 0; e < 8; e++) {
            float f = bf2f((ushort)v[e]);
            s += f * f;
        }
    }
    sq[idx] = s * kScale;
}

// ---------------------------------------------------------------------------
// K5: fused attention, work-split redesign (no redundant LDS reads).
// Block = 4 waves, 64 j-cols, 512 blocks (b=bid&7 XCD-pinned).
//  S-phase f-split : wave w computes S rows i in [16w,16w+16) for ALL 64 j
//                    (kj B-frags for 64 j live in 64 VGPRs, loaded once).
//                    A-frag reads: 4/wave/iter (was 16). P^T -> shared pt.
//  PV vd-split     : wave w computes vd in [64w,64w+64) for all 64 j.
//                    vfr reads 8, pfr reads 8 (was 32+2).
// Per-wave LDS traffic: 20KB/iter (was 50KB); block reads each tile once.
// dsum: per-wave partials -> small LDS cross-wave reduce at the end.
__global__ __launch_bounds__(256) void attn_kernel(const ushort* __restrict__ kt,
                                                   const ushort* __restrict__ vb,
                                                   const float* __restrict__ sq2,
                                                   float* __restrict__ out) {
    int bid = blockIdx.x;
    int b = bid & 7, jt = bid >> 3;
    int lane = threadIdx.x & 63, wv = threadIdx.x >> 6;
    int l15 = lane & 15, g = lane >> 4;

    __shared__ ushort bufK[64 * 128];      // 16KB: [i-row][swizzled 16B units]
    __shared__ ushort bufV[256 * 64];      // 32KB: [vd][swizzled 16B units]
    __shared__ ushort pt[64][72];          // 9KB: block-shared P^T [j][i]
    __shared__ float pdsum[4][4][16];      // 1KB: per-wave dsum partials

    const ushort* ktb = kt + ((size_t)b * Nn) * KD;
    const ushort* vbb = vb + ((size_t)b * VD) * Nn;
    const float* sqb = sq2 + b * Nn;

    // per-lane staging source pointers; LDS dests are wave-uniform
    const ushort* skp[4];
#pragma unroll
    for (int h = 0; h < 4; h++) {
        int row = wv * 16 + h * 4 + (lane >> 4);
        skp[h] = ktb + (size_t)row * KD + (((lane & 15) ^ (row & 7)) * 8);
    }
    const ushort* svp[8];
#pragma unroll
    for (int h = 0; h < 8; h++) {
        int vd = wv * 64 + h * 8 + (lane >> 3);
        svp[h] = vbb + (size_t)vd * Nn + (((lane & 7) ^ (vd & 7)) * 8);
    }

    // kj B-frags for the block's 64 j columns: [jsub][kk]
    short8_t kj[4][4];
    float sq2j[4];
#pragma unroll
    for (int s = 0; s < 4; s++) {
        int j = jt * 64 + s * 16 + l15;
        sq2j[s] = sqb[j];
#pragma unroll
        for (int kk = 0; kk < 4; kk++)
            kj[s][kk] = *(const short8_t*)(ktb + (size_t)j * KD + kk * 32 + g * 8);
    }

    floatx4 acc[4][4];   // [m(vd-tile)][s(j-sub)]
#pragma unroll
    for (int m = 0; m < 4; m++)
#pragma unroll
        for (int s = 0; s < 4; s++) acc[m][s] = (floatx4){0.f, 0.f, 0.f, 0.f};
    float dsumv[4] = {0.f, 0.f, 0.f, 0.f};
    const int swzA = l15 & 7;

    // prologue: stage K(0), V(0)
#pragma unroll
    for (int h = 0; h < 4; h++) gload_lds16(skp[h], &bufK[(wv * 16 + h * 4) * 128]);
#pragma unroll
    for (int h = 0; h < 8; h++) gload_lds16(svp[h], &bufV[(wv * 64 + h * 8) * 64]);
    __syncthreads();   // implicit vmcnt(0): both tiles resident

#pragma unroll 1
    for (int it = 0; it < 64; ++it) {
        int i0 = it * 64;

        // S-phase: wave wv owns i-rows [wv*16, wv*16+16) of the tile, all 64 j
        floatx4 sacc[4];
#pragma unroll
        for (int s = 0; s < 4; s++) sacc[s] = (floatx4){0.f, 0.f, 0.f, 0.f};
#pragma unroll
        for (int kk = 0; kk < 4; kk++) {
            short8_t afr = *(const short8_t*)&bufK[(wv * 16 + l15) * 128 + ((kk * 4 + g) ^ swzA) * 8];
#pragma unroll
            for (int s = 0; s < 4; s++)
                sacc[s] = __builtin_amdgcn_mfma_f32_16x16x32_bf16(afr, kj[s][kk], sacc[s], 0, 0, 0);
        }
        // P = exp2(TwoK*dot - sq2i - sq2j); pack bf16 pairs; write shared P^T
        floatx4 sqi = *(const floatx4*)(sqb + i0 + wv * 16 + g * 4);
#pragma unroll
        for (int s = 0; s < 4; s++) {
            float p0 = exp2f(sacc[s][0] * kTwoK - sqi[0] - sq2j[s]);
            float p1 = exp2f(sacc[s][1] * kTwoK - sqi[1] - sq2j[s]);
            float p2 = exp2f(sacc[s][2] * kTwoK - sqi[2] - sq2j[s]);
            float p3 = exp2f(sacc[s][3] * kTwoK - sqi[3] - sq2j[s]);
            dsumv[s] += (p0 + p1) + (p2 + p3);
            uint2 w2 = {pk_bf16(p0, p1), pk_bf16(p2, p3)};
            *(uint2*)&pt[s * 16 + l15][wv * 16 + g * 4] = w2;
        }
        __syncthreads();   // sync1: pt complete; all waves done reading bufK

        // issue K(it+1) prefetch (WAR-safe; drained by sync2's implicit vmcnt0)
        if (it < 63) {
#pragma unroll
            for (int h = 0; h < 4; h++)
                gload_lds16(skp[h] + (size_t)(i0 + 64) * KD, &bufK[(wv * 16 + h * 4) * 128]);
        }

        // PV: wave wv owns vd-rows [wv*64, wv*64+64), all 64 j
#pragma unroll
        for (int k2 = 0; k2 < 2; k2++) {
            short8_t pfr[4];
#pragma unroll
            for (int s = 0; s < 4; s++)
                pfr[s] = *(const short8_t*)&pt[s * 16 + l15][k2 * 32 + g * 8];
#pragma unroll
            for (int m = 0; m < 4; m++) {
                int row = wv * 64 + m * 16 + l15;
                short8_t vfr = *(const short8_t*)&bufV[row * 64 + ((k2 * 4 + g) ^ swzA) * 8];
#pragma unroll
                for (int s = 0; s < 4; s++)
                    acc[m][s] = __builtin_amdgcn_mfma_f32_16x16x32_bf16(vfr, pfr[s], acc[m][s], 0, 0, 0);
            }
        }
        __syncthreads();   // sync2: bufV/pt reads done; K prefetch drained

        // issue V(it+1) prefetch (drained at next iter's sync1)
        if (it < 63) {
#pragma unroll
            for (int h = 0; h < 8; h++)
                gload_lds16(svp[h] + (i0 + 64), &bufV[(wv * 64 + h * 8) * 64]);
        }
    }

    // cross-wave dsum reduce: wave partials cover i in [wv*16..) slices
#pragma unroll
    for (int s = 0; s < 4; s++) {
        dsumv[s] += __shfl_xor(dsumv[s], 16, 64);
        dsumv[s] += __shfl_xor(dsumv[s], 32, 64);
    }
    if (g == 0) {
#pragma unroll
        for (int s = 0; s < 4; s++) pdsum[wv][s][l15] = dsumv[s];
    }
    __syncthreads();
    float rden[4];
#pragma unroll
    for (int s = 0; s < 4; s++)
        rden[s] = 1.f / (((pdsum[0][s][l15] + pdsum[1][s][l15]) +
                          (pdsum[2][s][l15] + pdsum[3][s][l15])));

    // output: vd = wv*64 + m*16 + g*4 + r, j = jt*64 + s*16 + l15
    float* ob = out + ((size_t)(b * 512 + 256 + wv * 64)) * Nn + jt * 64 + l15;
#pragma unroll
    for (int m = 0; m < 4; m++) {
#pragma unroll
        for (int s = 0; s < 4; s++) {
#pragma unroll
            for (int r = 0; r < 4; r++) {
                int vd = m * 16 + g * 4 + r;
                ob[(size_t)vd * Nn + s * 16] = acc[m][s][r] * rden[s];
            }
        }
    }
}

// ---------------------------------------------------------------------------
extern "C" void kernel_launch(void* const* d_in, const int* in_sizes, int n_in,
                              void* d_out, int out_size, void* d_ws, size_t ws_size,
                              hipStream_t stream) {
    const float* x     = (const float*)d_in[0];
    const float* kw    = (const float*)d_in[1];
    const float* kbias = (const float*)d_in[2];
    const float* vw    = (const float*)d_in[3];
    const float* vbias = (const float*)d_in[4];
    float* out = (float*)d_out;  // reference output dtype is FLOAT32
    char* ws = (char*)d_ws;

    // workspace layout (bytes) — total 44,908,544
    constexpr size_t XPAD = 0;                         // 8*66*66*256*2 = 17,842,176
    constexpr size_t WTK  = 17842176;                  // 9*128*256*2   =    589,824
    constexpr size_t WTV  = 18432000;                  // 9*256*256*2   =  1,179,648
    constexpr size_t KT   = 19611648;                  // 8*4096*128*2  =  8,388,608
    constexpr size_t VB   = 28000256;                  // 8*256*4096*2  = 16,777,216
    constexpr size_t SQ   = 44777472;                  // 8*4096*4      =    131,072

    ushort* xpad = (ushort*)(ws + XPAD);
    ushort* wtk  = (ushort*)(ws + WTK);
    ushort* wtv  = (ushort*)(ws + WTV);
    ushort* ktw  = (ushort*)(ws + KT);
    ushort* vbw  = (ushort*)(ws + VB);
    float*  sqw  = (float*)(ws + SQ);

    hipMemsetAsync(xpad, 0, 17842176, stream);  // zero borders of padded input
    pad_transpose<<<dim3(2048), 256, 0, stream>>>(x, xpad);
    repack_w<<<dim3(384), 256, 0, stream>>>(kw, vw, wtk, wtv);
    conv_gemm<0, KD><<<dim3(512), 256, 0, stream>>>(xpad, wtk, kbias, ktw, nullptr, nullptr);
    conv_gemm<1, VD><<<dim3(1024), 256, 0, stream>>>(xpad, wtv, vbias, nullptr, out, vbw);
    sq_kernel<<<dim3(128), 256, 0, stream>>>(ktw, sqw);
    attn_kernel<<<dim3(512), 256, 0, stream>>>(ktw, vbw, sqw, out);
}

// Round 8
// 312.905 us; speedup vs baseline: 1.0912x; 1.0912x over previous
//
#include <hip/hip_runtime.h>
#include <hip/hip_bf16.h>
#include <cstdint>

// Problem constants
constexpr int Bb = 8, Cc = 256, Hh = 64, Ww = 64, Nn = 4096;
constexpr int KD = 128, VD = 256, HP = 66; // HP = padded spatial (64+2)

typedef __attribute__((ext_vector_type(8))) short short8_t;   // 8 bf16 (4 VGPR) MFMA frag
typedef __attribute__((ext_vector_type(4))) short shortx4;    // 4 bf16 packed store
typedef __attribute__((ext_vector_type(4))) float floatx4;    // MFMA accumulator

// kScale = log2(e)/sqrt(128); P = exp2(2*kScale*dot - kScale*sqi - kScale*sqj)
constexpr float kScale = 0.08838834764831845f * 1.4426950408889634f;
constexpr float kTwoK  = 2.0f * kScale;

static __device__ __forceinline__ ushort f2bf(float f) {
    union { float f; uint32_t u; } v{f};
    uint32_t r = v.u + 0x7FFFu + ((v.u >> 16) & 1u);  // RNE
    return (ushort)(r >> 16);
}
static __device__ __forceinline__ float bf2f(ushort b) {
    union { uint32_t u; float f; } v{(uint32_t)b << 16};
    return v.f;
}
// pack two f32 -> two bf16 in one u32 (RNE), single HW inst
static __device__ __forceinline__ uint32_t pk_bf16(float a, float b) {
    uint32_t r;
    asm("v_cvt_pk_bf16_f32 %0, %1, %2" : "=v"(r) : "v"(a), "v"(b));
    return r;
}

// async global->LDS, 16B per lane; lds base must be wave-uniform (HW adds lane*16)
static __device__ __forceinline__ void gload_lds16(const void* g, void* l) {
    __builtin_amdgcn_global_load_lds((const __attribute__((address_space(1))) uint32_t*)g,
                                     (__attribute__((address_space(3))) uint32_t*)l, 16, 0, 0);
}

// ---------------------------------------------------------------------------
// K1: x[b][c][y][x] (f32) -> xpad[b][y+1][x+1][c] (bf16, channel-last).
__global__ __launch_bounds__(256) void pad_transpose(const float* __restrict__ x,
                                                     ushort* __restrict__ xpad) {
    int bid = blockIdx.x;
    int b = bid & 7, rest = bid >> 3;
    int y = rest & 63, cg = rest >> 6;   // cg: 64-channel group
    int t = threadIdx.x;
    __shared__ float tile[64][65];
    int xcol = t & 63;
    int crow = t >> 6;  // 0..3
    const float* xb = x + ((size_t)(b * Cc + cg * 64) * Nn) + y * 64;
#pragma unroll
    for (int i = 0; i < 16; i++) {
        int c = crow + i * 4;
        tile[c][xcol] = xb[(size_t)c * Nn + xcol];
    }
    __syncthreads();
    int c = t & 63;
    int x4 = t >> 6;
    ushort* dst = xpad + (((size_t)(b * HP + (y + 1)) * HP) + 1) * Cc + cg * 64 + c;
#pragma unroll
    for (int i = 0; i < 16; i++) {
        int xx = x4 + i * 4;
        dst[(size_t)xx * Cc] = f2bf(tile[c][xx]);
    }
}

// ---------------------------------------------------------------------------
// K2: repack weights w[oc][c][3][3] (f32) -> wt[r][oc][c] (bf16), r = dy*3+dx
__global__ __launch_bounds__(256) void repack_w(const float* __restrict__ kw,
                                                const float* __restrict__ vw,
                                                ushort* __restrict__ wtk,
                                                ushort* __restrict__ wtv) {
    int idx = blockIdx.x * 256 + threadIdx.x;
    const int nk = KD * Cc;   // 32768
    const int nv = VD * Cc;   // 65536
    if (idx < nk) {
        const float* src = kw + (size_t)idx * 9;
        int oc = idx / Cc, c = idx % Cc;
#pragma unroll
        for (int r = 0; r < 9; r++) wtk[((size_t)r * KD + oc) * Cc + c] = f2bf(src[r]);
    } else if (idx < nk + nv) {
        int j = idx - nk;
        const float* src = vw + (size_t)j * 9;
        int oc = j / Cc, c = j % Cc;
#pragma unroll
        for (int r = 0; r < 9; r++) wtv[((size_t)r * VD + oc) * Cc + c] = f2bf(src[r]);
    }
}

// ---------------------------------------------------------------------------
// K3: implicit-GEMM conv3x3 via MFMA, weight slab LDS-staged (round-6 proven).
template <int MODE, int OC>
__global__ __launch_bounds__(256) void conv_gemm(const ushort* __restrict__ xpad,
                                                 const ushort* __restrict__ wt,
                                                 const float* __restrict__ bias,
                                                 ushort* __restrict__ kt_out,
                                                 float* __restrict__ f32_out,
                                                 ushort* __restrict__ vb_out) {
    int bid = blockIdx.x;
    int b = bid & 7;
    int ocg, y;
    if (OC == 128) { ocg = 0; y = bid >> 3; }
    else           { ocg = (bid >> 3) & 1; y = bid >> 4; }
    int lane = threadIdx.x & 63, wv = threadIdx.x >> 6;
    int l15 = lane & 15, g = lane >> 4;
    int oc0 = ocg * 128;
    const int swzA = l15 & 7;

    __shared__ ushort wslab[2][128 * 128];   // 2 x 32KB weight half-slabs

    size_t wsoff[8];
    int ldsrow[8];
#pragma unroll
    for (int h = 0; h < 8; h++) {
        int row = wv * 32 + h * 4 + (lane >> 4);      // oc row this lane stages
        wsoff[h] = (size_t)row * Cc + (((lane & 15) ^ (row & 7)) * 8);
        ldsrow[h] = (wv * 32 + h * 4) * 128;
    }

    floatx4 acc[8];
#pragma unroll
    for (int m = 0; m < 8; m++) acc[m] = (floatx4){0.f, 0.f, 0.f, 0.f};

    const ushort* xb = xpad + ((size_t)b * HP * HP) * Cc;
    int xcol = wv * 16 + l15;  // output x position (wave's 16 columns)

    auto stage = [&](int hs, int bi) {
        int r = hs >> 1, hc = hs & 1;
        const ushort* wb = wt + ((size_t)r * OC + oc0) * Cc + hc * 128;
#pragma unroll
        for (int h = 0; h < 8; h++)
            gload_lds16(wb + wsoff[h], &wslab[bi][ldsrow[h]]);
    };

    stage(0, 0);
    __syncthreads();   // implicit vmcnt(0): slab 0 resident

#pragma unroll 1
    for (int hs = 0; hs < 18; ++hs) {
        int bi = hs & 1;
        if (hs < 17) stage(hs + 1, bi ^ 1);   // prefetch; drained by end barrier

        int r = hs >> 1, hc = hs & 1;
        int dy = r / 3, dx = r % 3;
        const ushort* bsrc = xb + ((size_t)(y + dy) * HP + xcol + dx) * Cc + hc * 128 + g * 8;
#pragma unroll
        for (int cc = 0; cc < 4; cc++) {      // 4 k-steps of 32 channels
            short8_t bfrag = *(const short8_t*)(bsrc + cc * 32);
#pragma unroll
            for (int m = 0; m < 8; m++) {
                short8_t afrag = *(const short8_t*)&wslab[bi][(m * 16 + l15) * 128 + ((cc * 4 + g) ^ swzA) * 8];
                acc[m] = __builtin_amdgcn_mfma_f32_16x16x32_bf16(afrag, bfrag, acc[m], 0, 0, 0);
            }
        }
        __syncthreads();   // reads done + prefetch drained
    }

    int pos = y * 64 + xcol;
    if (MODE == 0) {
        ushort* kt = kt_out + ((size_t)(b * Nn + pos)) * KD;
#pragma unroll
        for (int m = 0; m < 8; m++) {
            floatx4 bv = *(const floatx4*)(bias + m * 16 + g * 4);
            shortx4 pk;
#pragma unroll
            for (int r = 0; r < 4; r++) pk[r] = (short)f2bf(acc[m][r] + bv[r]);
            *(shortx4*)(kt + m * 16 + g * 4) = pk;
        }
    } else {
#pragma unroll
        for (int m = 0; m < 8; m++) {
            floatx4 bv = *(const floatx4*)(bias + oc0 + m * 16 + g * 4);
#pragma unroll
            for (int r = 0; r < 4; r++) {
                int oc = oc0 + m * 16 + g * 4 + r;
                float v = acc[m][r] + bv[r];
                f32_out[((size_t)(b * 512 + oc)) * Nn + pos] = v;       // d_out f32
                vb_out[((size_t)(b * VD + oc)) * Nn + pos] = f2bf(v);   // bf16 for PV MFMA
            }
        }
    }
}

// ---------------------------------------------------------------------------
// K4: sq2[b*N+pos] = kScale * sum_ch Kt[pos][ch]^2 (scale pre-folded for attn).
__global__ __launch_bounds__(256) void sq_kernel(const ushort* __restrict__ kt,
                                                 float* __restrict__ sq) {
    int bid = blockIdx.x;
    int idx = (bid & 7) * Nn + (bid >> 3) * 256 + threadIdx.x;
    const ushort* src = kt + (size_t)idx * KD;
    float s = 0.f;
#pragma unroll
    for (int i = 0; i < 16; i++) {
        short8_t v = *(const short8_t*)(src + i * 8);
#pragma unroll
        for (int e = 0; e < 8; e++) {
            float f = bf2f((ushort)v[e]);
            s += f * f;
        }
    }
    sq[idx] = s * kScale;
}

// ---------------------------------------------------------------------------
// K5: fused attention — round-6 structure (waves fully independent, per-wave
// pt, 2-barrier schedule) with j=32 per wave (acc[16][2]) so every K/V LDS
// read feeds 2 MFMAs: LDS traffic + addressing per unit work HALVED vs r6.
// i-tile shrunk to 32 rows (128 iters) to fit LDS: bufK 8K + bufV 16K + pt 9K
// = 33KB. Each wave covers the FULL i-range -> dsum needs no cross-wave
// reduce. Block = 4 waves x 32 j = 128 j, grid 256 (b=bid&7 XCD-pinned).
__global__ __launch_bounds__(256, 2) void attn_kernel(const ushort* __restrict__ kt,
                                                      const ushort* __restrict__ vb,
                                                      const float* __restrict__ sq2,
                                                      float* __restrict__ out) {
    int bid = blockIdx.x;
    int b = bid & 7, jt = bid >> 3;          // jt in 0..31, 128 j per block
    int lane = threadIdx.x & 63, wv = threadIdx.x >> 6;
    int l15 = lane & 15, g = lane >> 4;

    __shared__ ushort bufK[32 * 128];      // 8KB: [i-row][swizzled 16B units]
    __shared__ ushort bufV[256 * 32];      // 16KB: [vd][swizzled 8-elem units]
    __shared__ ushort pt[4][32][36];       // 9KB: per-wave P^T [j][i(+pad)]

    const ushort* ktb = kt + ((size_t)b * Nn) * KD;
    const ushort* vbb = vb + ((size_t)b * VD) * Nn;
    const float* sqb = sq2 + b * Nn;

    // staging source pointers (it=0); LDS dests wave-uniform, sources
    // inverse-XOR-swizzled so linear LDS + swizzled read = conflict-free.
    const ushort* skp[2];
#pragma unroll
    for (int h = 0; h < 2; h++) {
        int row = wv * 8 + h * 4 + (lane >> 4);                 // i-row staged
        skp[h] = ktb + (size_t)row * KD + (((lane & 15) ^ (row & 7)) * 8);
    }
    const ushort* svp[4];
#pragma unroll
    for (int h = 0; h < 4; h++) {
        int vd = wv * 64 + h * 16 + (lane >> 2);                // vd row staged
        svp[h] = vbb + (size_t)vd * Nn + (((lane & 3) ^ (vd & 3)) * 8);
    }

    // kj B-frags + sq2j for this wave's 32 j columns (s=0,1 subtiles)
    short8_t kj[2][4];
    float sq2j[2];
#pragma unroll
    for (int s = 0; s < 2; s++) {
        int j = jt * 128 + wv * 32 + s * 16 + l15;
        sq2j[s] = sqb[j];
#pragma unroll
        for (int kk = 0; kk < 4; kk++)
            kj[s][kk] = *(const short8_t*)(ktb + (size_t)j * KD + kk * 32 + g * 8);
    }

    floatx4 acc[16][2];   // [m(vd-tile)][s(j-sub)]
#pragma unroll
    for (int m = 0; m < 16; m++)
#pragma unroll
        for (int s = 0; s < 2; s++) acc[m][s] = (floatx4){0.f, 0.f, 0.f, 0.f};
    float dsumv[2] = {0.f, 0.f};
    const int swzA = l15 & 7;

    // prologue: stage K(0), V(0)
#pragma unroll
    for (int h = 0; h < 2; h++) gload_lds16(skp[h], &bufK[(wv * 8 + h * 4) * 128]);
#pragma unroll
    for (int h = 0; h < 4; h++) gload_lds16(svp[h], &bufV[(wv * 64 + h * 16) * 32]);
    __syncthreads();   // implicit vmcnt(0): both tiles resident

#pragma unroll 1
    for (int it = 0; it < 128; ++it) {
        int i0 = it * 32;

        // S-phase: 8 afr reads, 16 MFMAs (each afr feeds both j-subtiles)
        floatx4 sacc[2][2];   // [f(i-sub)][s]
#pragma unroll
        for (int f = 0; f < 2; f++)
#pragma unroll
            for (int s = 0; s < 2; s++) sacc[f][s] = (floatx4){0.f, 0.f, 0.f, 0.f};
#pragma unroll
        for (int kk = 0; kk < 4; kk++) {
#pragma unroll
            for (int f = 0; f < 2; f++) {
                short8_t afr = *(const short8_t*)&bufK[(f * 16 + l15) * 128 + ((kk * 4 + g) ^ swzA) * 8];
#pragma unroll
                for (int s = 0; s < 2; s++)
                    sacc[f][s] = __builtin_amdgcn_mfma_f32_16x16x32_bf16(afr, kj[s][kk], sacc[f][s], 0, 0, 0);
            }
        }
        // P = exp2(TwoK*dot - sq2i - sq2j); pack pairs; write per-wave P^T
#pragma unroll
        for (int f = 0; f < 2; f++) {
            floatx4 sqi = *(const floatx4*)(sqb + i0 + f * 16 + g * 4);
#pragma unroll
            for (int s = 0; s < 2; s++) {
                float p0 = exp2f(sacc[f][s][0] * kTwoK - sqi[0] - sq2j[s]);
                float p1 = exp2f(sacc[f][s][1] * kTwoK - sqi[1] - sq2j[s]);
                float p2 = exp2f(sacc[f][s][2] * kTwoK - sqi[2] - sq2j[s]);
                float p3 = exp2f(sacc[f][s][3] * kTwoK - sqi[3] - sq2j[s]);
                dsumv[s] += (p0 + p1) + (p2 + p3);
                uint2 w2 = {pk_bf16(p0, p1), pk_bf16(p2, p3)};
                *(uint2*)&pt[wv][s * 16 + l15][f * 16 + g * 4] = w2;
            }
        }
        __syncthreads();   // sync1: V(it) resident; bufK reads done

        // issue K(it+1) prefetch (drained by sync2's implicit vmcnt0)
        if (it < 127) {
#pragma unroll
            for (int h = 0; h < 2; h++)
                gload_lds16(skp[h] + (size_t)(i0 + 32) * KD, &bufK[(wv * 8 + h * 4) * 128]);
        }

        // PV: 16 vfr reads, 2 pfr reads, 32 MFMAs (vfr feeds both j-subtiles)
        short8_t pfr[2];
#pragma unroll
        for (int s = 0; s < 2; s++)
            pfr[s] = *(const short8_t*)&pt[wv][s * 16 + l15][g * 8];
#pragma unroll
        for (int m = 0; m < 16; m++) {
            int row = m * 16 + l15;
            short8_t vfr = *(const short8_t*)&bufV[row * 32 + (g ^ (row & 3)) * 8];
#pragma unroll
            for (int s = 0; s < 2; s++)
                acc[m][s] = __builtin_amdgcn_mfma_f32_16x16x32_bf16(vfr, pfr[s], acc[m][s], 0, 0, 0);
        }
        __syncthreads();   // sync2: bufV/pt reads done; K prefetch drained

        // issue V(it+1) prefetch (drained at next iter's sync1)
        if (it < 127) {
#pragma unroll
            for (int h = 0; h < 4; h++)
                gload_lds16(svp[h] + (i0 + 32), &bufV[(wv * 64 + h * 16) * 32]);
        }
    }

    // denominator: lanes {l15, +16, +32, +48} hold the 4 g-slices of col j
#pragma unroll
    for (int s = 0; s < 2; s++) {
        dsumv[s] += __shfl_xor(dsumv[s], 16, 64);
        dsumv[s] += __shfl_xor(dsumv[s], 32, 64);
    }
    float rden[2] = {1.f / dsumv[0], 1.f / dsumv[1]};

    // output: vd = m*16 + g*4 + r, j = jt*128 + wv*32 + s*16 + l15
    float* ob = out + ((size_t)(b * 512 + 256)) * Nn + jt * 128 + wv * 32 + l15;
#pragma unroll
    for (int m = 0; m < 16; m++) {
#pragma unroll
        for (int s = 0; s < 2; s++) {
#pragma unroll
            for (int r = 0; r < 4; r++) {
                int vd = m * 16 + g * 4 + r;
                ob[(size_t)vd * Nn + s * 16] = acc[m][s][r] * rden[s];
            }
        }
    }
}

// ---------------------------------------------------------------------------
extern "C" void kernel_launch(void* const* d_in, const int* in_sizes, int n_in,
                              void* d_out, int out_size, void* d_ws, size_t ws_size,
                              hipStream_t stream) {
    const float* x     = (const float*)d_in[0];
    const float* kw    = (const float*)d_in[1];
    const float* kbias = (const float*)d_in[2];
    const float* vw    = (const float*)d_in[3];
    const float* vbias = (const float*)d_in[4];
    float* out = (float*)d_out;  // reference output dtype is FLOAT32
    char* ws = (char*)d_ws;

    // workspace layout (bytes) — total 44,908,544
    constexpr size_t XPAD = 0;                         // 8*66*66*256*2 = 17,842,176
    constexpr size_t WTK  = 17842176;                  // 9*128*256*2   =    589,824
    constexpr size_t WTV  = 18432000;                  // 9*256*256*2   =  1,179,648
    constexpr size_t KT   = 19611648;                  // 8*4096*128*2  =  8,388,608
    constexpr size_t VB   = 28000256;                  // 8*256*4096*2  = 16,777,216
    constexpr size_t SQ   = 44777472;                  // 8*4096*4      =    131,072

    ushort* xpad = (ushort*)(ws + XPAD);
    ushort* wtk  = (ushort*)(ws + WTK);
    ushort* wtv  = (ushort*)(ws + WTV);
    ushort* ktw  = (ushort*)(ws + KT);
    ushort* vbw  = (ushort*)(ws + VB);
    float*  sqw  = (float*)(ws + SQ);

    hipMemsetAsync(xpad, 0, 17842176, stream);  // zero borders of padded input
    pad_transpose<<<dim3(2048), 256, 0, stream>>>(x, xpad);
    repack_w<<<dim3(384), 256, 0, stream>>>(kw, vw, wtk, wtv);
    conv_gemm<0, KD><<<dim3(512), 256, 0, stream>>>(xpad, wtk, kbias, ktw, nullptr, nullptr);
    conv_gemm<1, VD><<<dim3(1024), 256, 0, stream>>>(xpad, wtv, vbias, nullptr, out, vbw);
    sq_kernel<<<dim3(128), 256, 0, stream>>>(ktw, sqw);
    attn_kernel<<<dim3(256), 256, 0, stream>>>(ktw, vbw, sqw, out);
}

// Round 9
// 306.998 us; speedup vs baseline: 1.1122x; 1.0192x over previous
//
#include <hip/hip_runtime.h>
#include <hip/hip_bf16.h>
#include <cstdint>

// Problem constants
constexpr int Bb = 8, Cc = 256, Hh = 64, Ww = 64, Nn = 4096;
constexpr int KD = 128, VD = 256, HP = 66; // HP = padded spatial (64+2)

typedef __attribute__((ext_vector_type(8))) short short8_t;   // 8 bf16 (4 VGPR) MFMA frag
typedef __attribute__((ext_vector_type(4))) short shortx4;    // 4 bf16 packed store
typedef __attribute__((ext_vector_type(4))) float floatx4;    // MFMA accumulator

// kScale = log2(e)/sqrt(128); P = exp2(2*kScale*dot - kScale*sqi - kScale*sqj)
constexpr float kScale = 0.08838834764831845f * 1.4426950408889634f;
constexpr float kTwoK  = 2.0f * kScale;

static __device__ __forceinline__ ushort f2bf(float f) {
    union { float f; uint32_t u; } v{f};
    uint32_t r = v.u + 0x7FFFu + ((v.u >> 16) & 1u);  // RNE
    return (ushort)(r >> 16);
}
static __device__ __forceinline__ float bf2f(ushort b) {
    union { uint32_t u; float f; } v{(uint32_t)b << 16};
    return v.f;
}
// pack two f32 -> two bf16 in one u32 (RNE), single HW inst
static __device__ __forceinline__ uint32_t pk_bf16(float a, float b) {
    uint32_t r;
    asm("v_cvt_pk_bf16_f32 %0, %1, %2" : "=v"(r) : "v"(a), "v"(b));
    return r;
}

// async global->LDS, 16B per lane; lds base must be wave-uniform (HW adds lane*16)
static __device__ __forceinline__ void gload_lds16(const void* g, void* l) {
    __builtin_amdgcn_global_load_lds((const __attribute__((address_space(1))) uint32_t*)g,
                                     (__attribute__((address_space(3))) uint32_t*)l, 16, 0, 0);
}

// ---------------------------------------------------------------------------
// K1: x[b][c][y][x] (f32) -> xpad[b][y+1][x+1][c] (bf16, channel-last).
__global__ __launch_bounds__(256) void pad_transpose(const float* __restrict__ x,
                                                     ushort* __restrict__ xpad) {
    int bid = blockIdx.x;
    int b = bid & 7, rest = bid >> 3;
    int y = rest & 63, cg = rest >> 6;   // cg: 64-channel group
    int t = threadIdx.x;
    __shared__ float tile[64][65];
    int xcol = t & 63;
    int crow = t >> 6;  // 0..3
    const float* xb = x + ((size_t)(b * Cc + cg * 64) * Nn) + y * 64;
#pragma unroll
    for (int i = 0; i < 16; i++) {
        int c = crow + i * 4;
        tile[c][xcol] = xb[(size_t)c * Nn + xcol];
    }
    __syncthreads();
    int c = t & 63;
    int x4 = t >> 6;
    ushort* dst = xpad + (((size_t)(b * HP + (y + 1)) * HP) + 1) * Cc + cg * 64 + c;
#pragma unroll
    for (int i = 0; i < 16; i++) {
        int xx = x4 + i * 4;
        dst[(size_t)xx * Cc] = f2bf(tile[c][xx]);
    }
}

// ---------------------------------------------------------------------------
// K2: repack weights w[oc][c][3][3] (f32) -> wt[r][oc][c] (bf16), r = dy*3+dx
__global__ __launch_bounds__(256) void repack_w(const float* __restrict__ kw,
                                                const float* __restrict__ vw,
                                                ushort* __restrict__ wtk,
                                                ushort* __restrict__ wtv) {
    int idx = blockIdx.x * 256 + threadIdx.x;
    const int nk = KD * Cc;   // 32768
    const int nv = VD * Cc;   // 65536
    if (idx < nk) {
        const float* src = kw + (size_t)idx * 9;
        int oc = idx / Cc, c = idx % Cc;
#pragma unroll
        for (int r = 0; r < 9; r++) wtk[((size_t)r * KD + oc) * Cc + c] = f2bf(src[r]);
    } else if (idx < nk + nv) {
        int j = idx - nk;
        const float* src = vw + (size_t)j * 9;
        int oc = j / Cc, c = j % Cc;
#pragma unroll
        for (int r = 0; r < 9; r++) wtv[((size_t)r * VD + oc) * Cc + c] = f2bf(src[r]);
    }
}

// ---------------------------------------------------------------------------
// K3: implicit-GEMM conv3x3 via MFMA, weight slab LDS-staged (round-6 proven).
template <int MODE, int OC>
__global__ __launch_bounds__(256) void conv_gemm(const ushort* __restrict__ xpad,
                                                 const ushort* __restrict__ wt,
                                                 const float* __restrict__ bias,
                                                 ushort* __restrict__ kt_out,
                                                 float* __restrict__ f32_out,
                                                 ushort* __restrict__ vb_out) {
    int bid = blockIdx.x;
    int b = bid & 7;
    int ocg, y;
    if (OC == 128) { ocg = 0; y = bid >> 3; }
    else           { ocg = (bid >> 3) & 1; y = bid >> 4; }
    int lane = threadIdx.x & 63, wv = threadIdx.x >> 6;
    int l15 = lane & 15, g = lane >> 4;
    int oc0 = ocg * 128;
    const int swzA = l15 & 7;

    __shared__ ushort wslab[2][128 * 128];   // 2 x 32KB weight half-slabs

    size_t wsoff[8];
    int ldsrow[8];
#pragma unroll
    for (int h = 0; h < 8; h++) {
        int row = wv * 32 + h * 4 + (lane >> 4);      // oc row this lane stages
        wsoff[h] = (size_t)row * Cc + (((lane & 15) ^ (row & 7)) * 8);
        ldsrow[h] = (wv * 32 + h * 4) * 128;
    }

    floatx4 acc[8];
#pragma unroll
    for (int m = 0; m < 8; m++) acc[m] = (floatx4){0.f, 0.f, 0.f, 0.f};

    const ushort* xb = xpad + ((size_t)b * HP * HP) * Cc;
    int xcol = wv * 16 + l15;  // output x position (wave's 16 columns)

    auto stage = [&](int hs, int bi) {
        int r = hs >> 1, hc = hs & 1;
        const ushort* wb = wt + ((size_t)r * OC + oc0) * Cc + hc * 128;
#pragma unroll
        for (int h = 0; h < 8; h++)
            gload_lds16(wb + wsoff[h], &wslab[bi][ldsrow[h]]);
    };

    stage(0, 0);
    __syncthreads();   // implicit vmcnt(0): slab 0 resident

#pragma unroll 1
    for (int hs = 0; hs < 18; ++hs) {
        int bi = hs & 1;
        if (hs < 17) stage(hs + 1, bi ^ 1);   // prefetch; drained by end barrier

        int r = hs >> 1, hc = hs & 1;
        int dy = r / 3, dx = r % 3;
        const ushort* bsrc = xb + ((size_t)(y + dy) * HP + xcol + dx) * Cc + hc * 128 + g * 8;
#pragma unroll
        for (int cc = 0; cc < 4; cc++) {      // 4 k-steps of 32 channels
            short8_t bfrag = *(const short8_t*)(bsrc + cc * 32);
#pragma unroll
            for (int m = 0; m < 8; m++) {
                short8_t afrag = *(const short8_t*)&wslab[bi][(m * 16 + l15) * 128 + ((cc * 4 + g) ^ swzA) * 8];
                acc[m] = __builtin_amdgcn_mfma_f32_16x16x32_bf16(afrag, bfrag, acc[m], 0, 0, 0);
            }
        }
        __syncthreads();   // reads done + prefetch drained
    }

    int pos = y * 64 + xcol;
    if (MODE == 0) {
        ushort* kt = kt_out + ((size_t)(b * Nn + pos)) * KD;
#pragma unroll
        for (int m = 0; m < 8; m++) {
            floatx4 bv = *(const floatx4*)(bias + m * 16 + g * 4);
            shortx4 pk;
#pragma unroll
            for (int r = 0; r < 4; r++) pk[r] = (short)f2bf(acc[m][r] + bv[r]);
            *(shortx4*)(kt + m * 16 + g * 4) = pk;
        }
    } else {
#pragma unroll
        for (int m = 0; m < 8; m++) {
            floatx4 bv = *(const floatx4*)(bias + oc0 + m * 16 + g * 4);
#pragma unroll
            for (int r = 0; r < 4; r++) {
                int oc = oc0 + m * 16 + g * 4 + r;
                float v = acc[m][r] + bv[r];
                f32_out[((size_t)(b * 512 + oc)) * Nn + pos] = v;       // d_out f32
                vb_out[((size_t)(b * VD + oc)) * Nn + pos] = f2bf(v);   // bf16 for PV MFMA
            }
        }
    }
}

// ---------------------------------------------------------------------------
// K4: sq2[b*N+pos] = kScale * sum_ch Kt[pos][ch]^2 (scale pre-folded for attn).
__global__ __launch_bounds__(256) void sq_kernel(const ushort* __restrict__ kt,
                                                 float* __restrict__ sq) {
    int bid = blockIdx.x;
    int idx = (bid & 7) * Nn + (bid >> 3) * 256 + threadIdx.x;
    const ushort* src = kt + (size_t)idx * KD;
    float s = 0.f;
#pragma unroll
    for (int i = 0; i < 16; i++) {
        short8_t v = *(const short8_t*)(src + i * 8);
#pragma unroll
        for (int e = 0; e < 8; e++) {
            float f = bf2f((ushort)v[e]);
            s += f * f;
        }
    }
    sq[idx] = s * kScale;
}

// ---------------------------------------------------------------------------
// K5: fused attention — vd-split for occupancy. Block = (b, jt, vh):
// j=128 (4 waves x 32 j), vd in [vh*128, vh*128+128), full i-range (128 iters
// of 32-row i-tiles). Grid 512 -> 2 blocks/CU (r8 had 256 -> 1/CU -> 1
// wave/SIMD -> all latency exposed; that was the r8 regression).
// S-phase is computed by both vd-halves (+33% MFMA at 20% util - cheap);
// PV/bufV/acc halve per block; outputs disjoint; dsum recomputed locally.
// LDS: bufK 8K + bufV 8K + pt 9K = 25KB. Every K/V LDS read feeds 2 MFMAs.
__global__ __launch_bounds__(256) void attn_kernel(const ushort* __restrict__ kt,
                                                   const ushort* __restrict__ vb,
                                                   const float* __restrict__ sq2,
                                                   float* __restrict__ out) {
    int bid = blockIdx.x;
    int b = bid & 7, rest = bid >> 3;        // 512 blocks: b, jt(0..31), vh(0..1)
    int jt = rest & 31, vh = rest >> 5;
    int vd0 = vh * 128;
    int lane = threadIdx.x & 63, wv = threadIdx.x >> 6;
    int l15 = lane & 15, g = lane >> 4;

    __shared__ ushort bufK[32 * 128];      // 8KB: [i-row][swizzled 16B units]
    __shared__ ushort bufV[128 * 32];      // 8KB: [vd-local][swizzled units]
    __shared__ ushort pt[4][32][36];       // 9KB: per-wave P^T [j][i(+pad)]

    const ushort* ktb = kt + ((size_t)b * Nn) * KD;
    const ushort* vbb = vb + ((size_t)(b * VD + vd0)) * Nn;
    const float* sqb = sq2 + b * Nn;

    // staging source pointers (it=0); LDS dests wave-uniform, sources
    // inverse-XOR-swizzled so linear LDS + swizzled read = conflict-free.
    const ushort* skp[2];
#pragma unroll
    for (int h = 0; h < 2; h++) {
        int row = wv * 8 + h * 4 + (lane >> 4);                 // i-row staged
        skp[h] = ktb + (size_t)row * KD + (((lane & 15) ^ (row & 7)) * 8);
    }
    const ushort* svp[2];
#pragma unroll
    for (int h = 0; h < 2; h++) {
        int vd = wv * 32 + h * 16 + (lane >> 2);                // vd-local staged
        svp[h] = vbb + (size_t)vd * Nn + (((lane & 3) ^ (vd & 3)) * 8);
    }

    // kj B-frags + sq2j for this wave's 32 j columns (s=0,1 subtiles)
    short8_t kj[2][4];
    float sq2j[2];
#pragma unroll
    for (int s = 0; s < 2; s++) {
        int j = jt * 128 + wv * 32 + s * 16 + l15;
        sq2j[s] = sqb[j];
#pragma unroll
        for (int kk = 0; kk < 4; kk++)
            kj[s][kk] = *(const short8_t*)(ktb + (size_t)j * KD + kk * 32 + g * 8);
    }

    floatx4 acc[8][2];   // [m(vd-tile, 128 vd)][s(j-sub)]
#pragma unroll
    for (int m = 0; m < 8; m++)
#pragma unroll
        for (int s = 0; s < 2; s++) acc[m][s] = (floatx4){0.f, 0.f, 0.f, 0.f};
    float dsumv[2] = {0.f, 0.f};
    const int swzA = l15 & 7;

    // prologue: stage K(0), V(0)
#pragma unroll
    for (int h = 0; h < 2; h++) gload_lds16(skp[h], &bufK[(wv * 8 + h * 4) * 128]);
#pragma unroll
    for (int h = 0; h < 2; h++) gload_lds16(svp[h], &bufV[(wv * 32 + h * 16) * 32]);
    __syncthreads();   // implicit vmcnt(0): both tiles resident

#pragma unroll 1
    for (int it = 0; it < 128; ++it) {
        int i0 = it * 32;

        // S-phase: 8 afr reads, 16 MFMAs (each afr feeds both j-subtiles)
        floatx4 sacc[2][2];   // [f(i-sub)][s]
#pragma unroll
        for (int f = 0; f < 2; f++)
#pragma unroll
            for (int s = 0; s < 2; s++) sacc[f][s] = (floatx4){0.f, 0.f, 0.f, 0.f};
#pragma unroll
        for (int kk = 0; kk < 4; kk++) {
#pragma unroll
            for (int f = 0; f < 2; f++) {
                short8_t afr = *(const short8_t*)&bufK[(f * 16 + l15) * 128 + ((kk * 4 + g) ^ swzA) * 8];
#pragma unroll
                for (int s = 0; s < 2; s++)
                    sacc[f][s] = __builtin_amdgcn_mfma_f32_16x16x32_bf16(afr, kj[s][kk], sacc[f][s], 0, 0, 0);
            }
        }
        // P = exp2(TwoK*dot - sq2i - sq2j); pack pairs; write per-wave P^T
#pragma unroll
        for (int f = 0; f < 2; f++) {
            floatx4 sqi = *(const floatx4*)(sqb + i0 + f * 16 + g * 4);
#pragma unroll
            for (int s = 0; s < 2; s++) {
                float p0 = exp2f(sacc[f][s][0] * kTwoK - sqi[0] - sq2j[s]);
                float p1 = exp2f(sacc[f][s][1] * kTwoK - sqi[1] - sq2j[s]);
                float p2 = exp2f(sacc[f][s][2] * kTwoK - sqi[2] - sq2j[s]);
                float p3 = exp2f(sacc[f][s][3] * kTwoK - sqi[3] - sq2j[s]);
                dsumv[s] += (p0 + p1) + (p2 + p3);
                uint2 w2 = {pk_bf16(p0, p1), pk_bf16(p2, p3)};
                *(uint2*)&pt[wv][s * 16 + l15][f * 16 + g * 4] = w2;
            }
        }
        __syncthreads();   // sync1: bufK reads done (all waves)

        // issue K(it+1) prefetch (drained by sync2's implicit vmcnt0)
        if (it < 127) {
#pragma unroll
            for (int h = 0; h < 2; h++)
                gload_lds16(skp[h] + (size_t)(i0 + 32) * KD, &bufK[(wv * 8 + h * 4) * 128]);
        }

        // PV: 8 vfr reads, 2 pfr reads, 16 MFMAs (vfr feeds both j-subtiles)
        short8_t pfr[2];
#pragma unroll
        for (int s = 0; s < 2; s++)
            pfr[s] = *(const short8_t*)&pt[wv][s * 16 + l15][g * 8];
#pragma unroll
        for (int m = 0; m < 8; m++) {
            int row = m * 16 + l15;   // vd-local
            short8_t vfr = *(const short8_t*)&bufV[row * 32 + (g ^ (row & 3)) * 8];
#pragma unroll
            for (int s = 0; s < 2; s++)
                acc[m][s] = __builtin_amdgcn_mfma_f32_16x16x32_bf16(vfr, pfr[s], acc[m][s], 0, 0, 0);
        }
        __syncthreads();   // sync2: bufV reads done; K prefetch drained

        // issue V(it+1) prefetch (drained at next iter's sync1)
        if (it < 127) {
#pragma unroll
            for (int h = 0; h < 2; h++)
                gload_lds16(svp[h] + (i0 + 32), &bufV[(wv * 32 + h * 16) * 32]);
        }
    }

    // denominator: lanes {l15, +16, +32, +48} hold the 4 g-slices of col j
#pragma unroll
    for (int s = 0; s < 2; s++) {
        dsumv[s] += __shfl_xor(dsumv[s], 16, 64);
        dsumv[s] += __shfl_xor(dsumv[s], 32, 64);
    }
    float rden[2] = {1.f / dsumv[0], 1.f / dsumv[1]};

    // output: vd = vd0 + m*16 + g*4 + r, j = jt*128 + wv*32 + s*16 + l15
    float* ob = out + ((size_t)(b * 512 + 256 + vd0)) * Nn + jt * 128 + wv * 32 + l15;
#pragma unroll
    for (int m = 0; m < 8; m++) {
#pragma unroll
        for (int s = 0; s < 2; s++) {
#pragma unroll
            for (int r = 0; r < 4; r++) {
                int vd = m * 16 + g * 4 + r;
                ob[(size_t)vd * Nn + s * 16] = acc[m][s][r] * rden[s];
            }
        }
    }
}

// ---------------------------------------------------------------------------
extern "C" void kernel_launch(void* const* d_in, const int* in_sizes, int n_in,
                              void* d_out, int out_size, void* d_ws, size_t ws_size,
                              hipStream_t stream) {
    const float* x     = (const float*)d_in[0];
    const float* kw    = (const float*)d_in[1];
    const float* kbias = (const float*)d_in[2];
    const float* vw    = (const float*)d_in[3];
    const float* vbias = (const float*)d_in[4];
    float* out = (float*)d_out;  // reference output dtype is FLOAT32
    char* ws = (char*)d_ws;

    // workspace layout (bytes) — total 44,908,544
    constexpr size_t XPAD = 0;                         // 8*66*66*256*2 = 17,842,176
    constexpr size_t WTK  = 17842176;                  // 9*128*256*2   =    589,824
    constexpr size_t WTV  = 18432000;                  // 9*256*256*2   =  1,179,648
    constexpr size_t KT   = 19611648;                  // 8*4096*128*2  =  8,388,608
    constexpr size_t VB   = 28000256;                  // 8*256*4096*2  = 16,777,216
    constexpr size_t SQ   = 44777472;                  // 8*4096*4      =    131,072

    ushort* xpad = (ushort*)(ws + XPAD);
    ushort* wtk  = (ushort*)(ws + WTK);
    ushort* wtv  = (ushort*)(ws + WTV);
    ushort* ktw  = (ushort*)(ws + KT);
    ushort* vbw  = (ushort*)(ws + VB);
    float*  sqw  = (float*)(ws + SQ);

    hipMemsetAsync(xpad, 0, 17842176, stream);  // zero borders of padded input
    pad_transpose<<<dim3(2048), 256, 0, stream>>>(x, xpad);
    repack_w<<<dim3(384), 256, 0, stream>>>(kw, vw, wtk, wtv);
    conv_gemm<0, KD><<<dim3(512), 256, 0, stream>>>(xpad, wtk, kbias, ktw, nullptr, nullptr);
    conv_gemm<1, VD><<<dim3(1024), 256, 0, stream>>>(xpad, wtv, vbias, nullptr, out, vbw);
    sq_kernel<<<dim3(128), 256, 0, stream>>>(ktw, sqw);
    attn_kernel<<<dim3(512), 256, 0, stream>>>(ktw, vbw, sqw, out);
}